// Round 10
// baseline (50.740 us; speedup 1.0000x reference)
//
#include <hip/hip_runtime.h>

// PointPillarsScatter: out[b][c][y][x] = sum_{p: coords[p]=(b,_,y,x)} vf[p][c]
// B=4, C=64, NY=496, NX=432, P=48000. Output (B,C,NY,NX) f32 ~219 MB.
//
// FINAL (reversion to session-best R3 configuration, 47.24 us):
//   k1 init : head[cell] = -1 (grid-stride int4 fill of 3.4 MB in d_ws)
//   k2 build: per-pillar linked list via atomicExch (head/nxt in d_ws)
//   k3 gather: per block 256 cells x 64 ch; per thread 4 cells x 16 ch.
//              Heads staged in LDS, chain walked once per cell, float4 vf
//              loads, 16 x 1KB/wave plain float4 coalesced stores.
//
// Falsified along the way (kept as session record):
//   - atomicAdd scatter: 150 us (atomic RMW serialization, R1)
//   - cooperative fused 3-phase: fails graph capture; direct-launch 395 us
//     (grid.sync oversubscription, R4/R5)
//   - nontemporal stores: +9 us (~25% store-BW penalty bypassing L2, R6)
//   - interleaved 4-chain lock-step walk + direct head loads: neutral (R8)
//   - 4KB-contiguous-per-plane re-tiling (grid 837x4): +3 us (R9)
// Plateau 47.2-47.8 us across all sane variants ~= 219.4 MB compulsory write
// at ~5.5-6 TB/s mixed-stream rate + ~5 us init/build/graph-node overhead.

#define CC 64
#define GNY 496
#define GNX 432
#define S_CELLS (GNY * GNX)         // 214272 (divisible by 256)
#define NUM_CELLS (4 * S_CELLS)     // 857088
#define NTILES (NUM_CELLS / 256)    // 3348

__global__ void pp_init_head(int4* __restrict__ head4, int n4) {
    int stride = gridDim.x * blockDim.x;
    for (int i = blockIdx.x * blockDim.x + threadIdx.x; i < n4; i += stride)
        head4[i] = make_int4(-1, -1, -1, -1);
}

__global__ void pp_build(const int* __restrict__ coords,
                         int* __restrict__ head,
                         int* __restrict__ nxt,
                         int P) {
    int p = blockIdx.x * blockDim.x + threadIdx.x;
    if (p >= P) return;
    int b = coords[p * 4 + 0];
    int y = coords[p * 4 + 2];
    int x = coords[p * 4 + 3];
    int s = (b * GNY + y) * GNX + x;
    nxt[p] = atomicExch(&head[s], p);
}

__global__ __launch_bounds__(256)
void pp_gather(const float4* __restrict__ vf4,
               const int* __restrict__ head,
               const int* __restrict__ nxt,
               float* __restrict__ out) {
    __shared__ alignas(16) int lds[256];
    int t = threadIdx.x;
    lds[t] = head[blockIdx.x * 256 + t];
    __syncthreads();

    int lane = t & 63;
    int cgp = t >> 6;                      // channel group: channels cgp*16..+15
    int s0 = blockIdx.x * 256 + lane * 4;  // 4 consecutive cells
    int b = s0 / S_CELLS;                  // tiles never straddle batches
    int r0 = s0 - b * S_CELLS;

    int4 h4 = ((const int4*)lds)[lane];    // ds_read_b128
    int hh[4] = {h4.x, h4.y, h4.z, h4.w};

    float acc[4][16];
    #pragma unroll
    for (int cell = 0; cell < 4; ++cell)
        #pragma unroll
        for (int i = 0; i < 16; ++i)
            acc[cell][i] = 0.f;

    #pragma unroll
    for (int cell = 0; cell < 4; ++cell) {
        for (int p = hh[cell]; p >= 0; ) {
            int pn = nxt[p];
            int pb = p * 16 + cgp * 4;     // float4 index into vf
            #pragma unroll
            for (int j = 0; j < 4; ++j) {
                float4 v = vf4[pb + j];
                acc[cell][4 * j + 0] += v.x;
                acc[cell][4 * j + 1] += v.y;
                acc[cell][4 * j + 2] += v.z;
                acc[cell][4 * j + 3] += v.w;
            }
            p = pn;
        }
    }

    size_t outbase = (size_t)b * (CC * S_CELLS)
                   + (size_t)(cgp * 16) * S_CELLS + r0;
    #pragma unroll
    for (int i = 0; i < 16; ++i) {
        float4 o = make_float4(acc[0][i], acc[1][i], acc[2][i], acc[3][i]);
        *(float4*)&out[outbase + (size_t)i * S_CELLS] = o;
    }
}

extern "C" void kernel_launch(void* const* d_in, const int* in_sizes, int n_in,
                              void* d_out, int out_size, void* d_ws, size_t ws_size,
                              hipStream_t stream) {
    const float* vf     = (const float*)d_in[0];
    const int*   coords = (const int*)d_in[1];
    float*       out    = (float*)d_out;

    int P = in_sizes[1] / 4;                      // 48000

    size_t need = (size_t)(NUM_CELLS + P) * sizeof(int);
    if (ws_size < need) return;                   // cannot happen per harness sizing

    int* head = (int*)d_ws;
    int* nxt  = head + NUM_CELLS;

    pp_init_head<<<512, 256, 0, stream>>>((int4*)head, NUM_CELLS / 4);
    pp_build<<<(P + 255) / 256, 256, 0, stream>>>(coords, head, nxt, P);
    pp_gather<<<NTILES, 256, 0, stream>>>((const float4*)vf, head, nxt, out);
}